// Round 9
// baseline (17.286 us; speedup 1.0000x reference)
//
#include <hip/hip_runtime.h>

#define NB 16
#define NA 3
#define NC 80
#define NH 76
#define NW 76
#define MAX_GT 50
#define PLANE (NH * NW)       // 5776
#define CH (5 + NC)           // 85
#define IMG 608.0f
#define OBJSC 5.0f
#define BLOCK 256
#define CPB 512                              // cells per block (2 adjacent per thread)
#define BPP ((PLANE + CPB - 1) / CPB)        // 12
#define GRID (NB * NA * BPP)                 // 576
#define KSIL 0.375f                          // SIL/(1+SIL), SIL=0.6

__device__ __constant__ float c_aw[3] = {1.5f, 2.375f, 5.0f};
__device__ __constant__ float c_ah[3] = {2.0f, 4.5f, 3.5f};

__device__ inline float fast_sigmoid(float v) {
    return __builtin_amdgcn_rcpf(1.f + __expf(-v));
}

__device__ inline float iou_full(float x1, float y1, float w1, float h1,
                                 float x2, float y2, float w2, float h2) {
    float mx = fminf(x1 - w1 * 0.5f, x2 - w2 * 0.5f);
    float Mx = fmaxf(x1 + w1 * 0.5f, x2 + w2 * 0.5f);
    float my = fminf(y1 - h1 * 0.5f, y2 - h2 * 0.5f);
    float My = fmaxf(y1 + h1 * 0.5f, y2 + h2 * 0.5f);
    float cw = w1 + w2 - (Mx - mx);
    float ch = h1 + h2 - (My - my);
    float carea = (cw <= 0.f || ch <= 0.f) ? 0.f : cw * ch;
    float uarea = w1 * h1 + w2 * h2 - carea;
    return carea / uarea;
}

// Fused kernel. Prep is now SINGLE-ROUND (target loads only — no pred-box
// gather): the GT-cell conf term (which needs iou(gt, pred@cell)) moved into
// the CE phase, whose 5 extra scalar loads ride the CE prefetch latency round
// and hide under the dense phase.
__global__ __launch_bounds__(BLOCK) void yolo_fused(const float* __restrict__ out,
                                                    const float* __restrict__ target,
                                                    float* __restrict__ partial) {
    const int bid = blockIdx.x;
    const int plane_id = bid / BPP;
    const int cb = bid % BPP;
    const int b = plane_id / NA;
    const int a = plane_id % NA;
    const int t = threadIdx.x;
    const int cell0 = cb * CPB + 2 * t;      // even; pair never straddles PLANE
    const int cell1 = cell0 + 1;
    const bool valid = (cell0 < PLANE);
    const float jminf = (float)((cb * CPB) / NW);
    const float jmaxf = (float)((min(cb * CPB + CPB, PLANE) - 1) / NW);

    __shared__ float4 s_gtA[MAX_GT];          // culled: xlo, xhi, ylo, yhi
    __shared__ float4 s_gtB[MAX_GT];          // culled: gw, gh, KSIL*area, 0
    __shared__ float s_ent[MAX_GT][12];       // 1:tx 2:ty 3:tw 4:th 5:gx 6:cls 7:gy 8:gw 9:gh 10:aw 11:ah
    __shared__ int s_ovr[CPB];                // local cell -> GT index (atomicMax)
    __shared__ int s_ce_cell[MAX_GT];
    __shared__ int s_ce_ov[MAX_GT];
    __shared__ int s_nv, s_nk, s_nce;
    __shared__ float s_red[BLOCK / 64];

    // ---- dense channel loads: float2 per channel, issued first ----
    const float* base = out + ((size_t)(b * NA + a) * CH) * PLANE;
    float2 v0 = {0.f, 0.f}, v1c = {0.f, 0.f}, v2c = {0.f, 0.f},
           v3c = {0.f, 0.f}, v4c = {0.f, 0.f};
    if (valid) {
        v0  = *(const float2*)&base[cell0];
        v1c = *(const float2*)&base[cell0 + PLANE];
        v2c = *(const float2*)&base[cell0 + 2 * (size_t)PLANE];
        v3c = *(const float2*)&base[cell0 + 3 * (size_t)PLANE];
        v4c = *(const float2*)&base[cell0 + 4 * (size_t)PLANE];
    }

    s_ovr[t] = -1;
    s_ovr[t + BLOCK] = -1;
    if (t == 0) s_nce = 0;

    // ---- prep: wave 0 only, ONE memory round (target only) ----
    int key = -1;
    if (t < 64) {
        float pxr = 1.f;
        float xlo = 0.f, xhi = 0.f, ylo = 0.f, yhi = 0.f, gw = 0.f, gh = 0.f;
        if (t < MAX_GT) {
            const float* tg = target + (size_t)b * MAX_GT * 5 + t * 5;
            float gcls = tg[0];
            pxr = tg[1];
            float gx = tg[1] * (float)NW / IMG;
            float gy = tg[2] * (float)NH / IMG;
            gw = tg[3] * (float)NW / IMG;
            gh = tg[4] * (float)NH / IMG;
            xlo = gx - 0.5f * gw; xhi = gx + 0.5f * gw;
            ylo = gy - 0.5f * gh; yhi = gy + 0.5f * gh;

            // best anchor (first-max wins); boxes co-centered at 0
            int bn = 0; float best = -1.f;
            #pragma unroll
            for (int aa = 0; aa < NA; aa++) {
                float ca = fminf(gw, c_aw[aa]) * fminf(gh, c_ah[aa]);
                float ua = gw * gh + c_aw[aa] * c_ah[aa] - ca;
                float v = ca / ua;
                if (v > best) { best = v; bn = aa; }
            }
            int gi = (int)gx, gj = (int)gy;

            key = (gi >= 0 && gi < NW && gj >= 0 && gj < NH)
                      ? ((bn * NH + gj) * NW + gi) : -1;
            s_ent[t][1] = gx - (float)gi;
            s_ent[t][2] = gy - (float)gj;
            s_ent[t][3] = __logf(gw / c_aw[bn]);
            s_ent[t][4] = __logf(gh / c_ah[bn]);
            s_ent[t][5] = gx;
            s_ent[t][6] = gcls;
            s_ent[t][7] = gy;
            s_ent[t][8] = gw;
            s_ent[t][9] = gh;
            s_ent[t][10] = c_aw[bn];
            s_ent[t][11] = c_ah[bn];
        }
        unsigned long long zm = __ballot((t < MAX_GT) && (pxr == 0.f));
        int nv = zm ? (int)(__ffsll((long long)zm) - 1) : MAX_GT;
        if (t == 0) s_nv = nv;

        // Y-band cull for the silence loop (conservative; see R7 derivation)
        bool keep = (t < nv) &&
                    (jmaxf + 0.75f > ylo - 0.25f * gh - 1.0f) &&
                    (jminf - 0.75f < yhi + 0.25f * gh);
        unsigned long long km = __ballot(keep);
        if (keep) {
            int pos = (int)__popcll(km & ((1ull << t) - 1ull));
            s_gtA[pos] = make_float4(xlo, xhi, ylo, yhi);
            s_gtB[pos] = make_float4(gw, gh, KSIL * gw * gh, 0.f);
        }
        if (t == 0) s_nk = (int)__popcll(km);
    }
    __syncthreads();

    // ---- scatter: last-write-wins = highest GT index via atomicMax ----
    if (t < s_nv && key >= 0) {
        int ae = key / PLANE;
        int local = (key - ae * PLANE) - cb * CPB;
        if (ae == a && local >= 0 && local < CPB) atomicMax(&s_ovr[local], t);
    }
    __syncthreads();

    // ---- build CE list from this thread's two cells ----
    int ovA = valid ? s_ovr[2 * t] : -1;
    int ovB = valid ? s_ovr[2 * t + 1] : -1;
    if (ovA >= 0) {
        int idx = atomicAdd(&s_nce, 1);
        s_ce_cell[idx] = cell0; s_ce_ov[idx] = ovA;
    }
    if (ovB >= 0) {
        int idx = atomicAdd(&s_nce, 1);
        s_ce_cell[idx] = cell1; s_ce_ov[idx] = ovB;
    }
    __syncthreads();

    const int nce = s_nce;
    const int wid = t >> 6, lane = t & 63;
    const float* cls_base = base + 5 * (size_t)PLANE;

    // ---- CE prefetch: first entry per wave; lane 0 also loads the cell's
    //      ch0-4 scalars for the deferred iou/conf term. All issue BEFORE dense.
    float ce1 = 0.f, ce2 = -3.4e38f, celt = 0.f;
    float q0 = 0.f, q1 = 0.f, q2 = 0.f, q3 = 0.f, q4 = 0.f;
    int pcell = 0, pov = 0;
    const bool havece = (wid < nce);
    if (havece) {
        pcell = s_ce_cell[wid];
        pov = s_ce_ov[wid];
        int ccls = (int)s_ent[pov][6];
        const float* cb0 = cls_base + pcell;
        ce1 = cb0[(size_t)lane * PLANE];
        if (lane < NC - 64) ce2 = cb0[(size_t)(lane + 64) * PLANE];
        celt = cb0[(size_t)ccls * PLANE];
        if (lane == 0) {
            q0 = base[pcell];
            q1 = base[pcell + PLANE];
            q2 = base[pcell + 2 * (size_t)PLANE];
            q3 = base[pcell + 3 * (size_t)PLANE];
            q4 = base[pcell + 4 * (size_t)PLANE];
        }
    }

    // ---- dense loss for both cells ----
    float loss = 0.f;
    if (valid) {
        int j0 = cell0 / NW, i0 = cell0 - j0 * NW;
        int j1 = cell1 / NW, i1 = cell1 - j1 * NW;

        float x0 = fast_sigmoid(v0.x), y0 = fast_sigmoid(v1c.x), cf0 = fast_sigmoid(v4c.x);
        float pw0 = __expf(v2c.x) * c_aw[a], ph0 = __expf(v3c.x) * c_ah[a];
        float px0 = x0 + (float)i0, py0 = y0 + (float)j0;
        float xl0 = px0 - 0.5f * pw0, xh0 = px0 + 0.5f * pw0;
        float yl0 = py0 - 0.5f * ph0, yh0 = py0 + 0.5f * ph0;
        float kpa0 = KSIL * pw0 * ph0;

        float x1 = fast_sigmoid(v0.y), y1 = fast_sigmoid(v1c.y), cf1 = fast_sigmoid(v4c.y);
        float pw1 = __expf(v2c.y) * c_aw[a], ph1 = __expf(v3c.y) * c_ah[a];
        float px1 = x1 + (float)i1, py1 = y1 + (float)j1;
        float xl1 = px1 - 0.5f * pw1, xh1 = px1 + 0.5f * pw1;
        float yl1 = py1 - 0.5f * ph1, yh1 = py1 + 0.5f * ph1;
        float kpa1 = KSIL * pw1 * ph1;

        bool sil0 = false, sil1 = false;
        int nk = s_nk;
        for (int tt = 0; tt < nk; tt++) {
            float4 gA = s_gtA[tt];
            float4 gB = s_gtB[tt];
            {
                float mx = fminf(xl0, gA.x), Mx = fmaxf(xh0, gA.y);
                float my = fminf(yl0, gA.z), My = fmaxf(yh0, gA.w);
                float cw = (pw0 + gB.x) - (Mx - mx);
                float ch = (ph0 + gB.y) - (My - my);
                sil0 |= (fminf(cw, ch) > 0.f) & (cw * ch > kpa0 + gB.z);
            }
            {
                float mx = fminf(xl1, gA.x), Mx = fmaxf(xh1, gA.y);
                float my = fminf(yl1, gA.z), My = fmaxf(yh1, gA.w);
                float cw = (pw1 + gB.x) - (Mx - mx);
                float ch = (ph1 + gB.y) - (My - my);
                sil1 |= (fminf(cw, ch) > 0.f) & (cw * ch > kpa1 + gB.z);
            }
        }

        {
            // conf term: non-GT only (GT-cell conf handled in CE phase)
            float cm = (ovA >= 0) ? 0.f : (sil0 ? 0.f : 1.f);
            float tx = 0.5f, ty = 0.5f, tw = 0.f, th = 0.f;
            if (ovA >= 0) {
                tx = s_ent[ovA][1]; ty = s_ent[ovA][2];
                tw = s_ent[ovA][3]; th = s_ent[ovA][4];
            }
            float dx = x0 - tx, dy = y0 - ty, dw = v2c.x - tw, dh = v3c.x - th;
            loss += 0.5f * (dx * dx + dy * dy + dw * dw + dh * dh + cm * cf0 * cf0);
        }
        {
            float cm = (ovB >= 0) ? 0.f : (sil1 ? 0.f : 1.f);
            float tx = 0.5f, ty = 0.5f, tw = 0.f, th = 0.f;
            if (ovB >= 0) {
                tx = s_ent[ovB][1]; ty = s_ent[ovB][2];
                tw = s_ent[ovB][3]; th = s_ent[ovB][4];
            }
            float dx = x1 - tx, dy = y1 - ty, dw = v2c.y - tw, dh = v3c.y - th;
            loss += 0.5f * (dx * dx + dy * dy + dw * dw + dh * dh + cm * cf1 * cf1);
        }
    }

    // ---- CE finish (prefetched entry): softmax-CE + deferred GT conf term ----
    if (havece) {
        float m = fmaxf(ce1, ce2);
        #pragma unroll
        for (int off = 32; off; off >>= 1) m = fmaxf(m, __shfl_xor(m, off));
        float e = __expf(ce1 - m) + ((lane < NC - 64) ? __expf(ce2 - m) : 0.f);
        #pragma unroll
        for (int off = 32; off; off >>= 1) e += __shfl_xor(e, off);
        if (lane == 0) {
            int gjc = pcell / NW, gic = pcell - gjc * NW;
            float ppx = fast_sigmoid(q0) + (float)gic;
            float ppy = fast_sigmoid(q1) + (float)gjc;
            float ppw = __expf(q2) * s_ent[pov][10];
            float pph = __expf(q3) * s_ent[pov][11];
            float iou = iou_full(s_ent[pov][5], s_ent[pov][7],
                                 s_ent[pov][8], s_ent[pov][9],
                                 ppx, ppy, ppw, pph);
            float dcf = fast_sigmoid(q4) - iou;
            loss += m + __logf(e) - celt + 0.5f * OBJSC * dcf * dcf;
        }
    }
    // leftover CE entries (rare: >4 GT cells in one chunk)
    for (int k = wid + 4; k < nce; k += 4) {
        int ccell = s_ce_cell[k];
        int ov = s_ce_ov[k];
        int ccls = (int)s_ent[ov][6];
        const float* cb0 = cls_base + ccell;
        float w1 = cb0[(size_t)lane * PLANE];
        float w2 = (lane < NC - 64) ? cb0[(size_t)(lane + 64) * PLANE] : -3.4e38f;
        float m = fmaxf(w1, w2);
        #pragma unroll
        for (int off = 32; off; off >>= 1) m = fmaxf(m, __shfl_xor(m, off));
        float e = __expf(w1 - m) + ((lane < NC - 64) ? __expf(w2 - m) : 0.f);
        #pragma unroll
        for (int off = 32; off; off >>= 1) e += __shfl_xor(e, off);
        if (lane == 0) {
            int gjc = ccell / NW, gic = ccell - gjc * NW;
            float r0 = base[ccell];
            float r1 = base[ccell + PLANE];
            float r2 = base[ccell + 2 * (size_t)PLANE];
            float r3 = base[ccell + 3 * (size_t)PLANE];
            float r4 = base[ccell + 4 * (size_t)PLANE];
            float ppx = fast_sigmoid(r0) + (float)gic;
            float ppy = fast_sigmoid(r1) + (float)gjc;
            float ppw = __expf(r2) * s_ent[ov][10];
            float pph = __expf(r3) * s_ent[ov][11];
            float iou = iou_full(s_ent[ov][5], s_ent[ov][7],
                                 s_ent[ov][8], s_ent[ov][9],
                                 ppx, ppy, ppw, pph);
            float dcf = fast_sigmoid(r4) - iou;
            loss += m + __logf(e) - cb0[(size_t)ccls * PLANE] + 0.5f * OBJSC * dcf * dcf;
        }
    }

    // ---- block reduction -> partial store ----
    #pragma unroll
    for (int off = 32; off; off >>= 1) loss += __shfl_down(loss, off);
    if (lane == 0) s_red[wid] = loss;
    __syncthreads();
    if (t == 0) {
        float s = 0.f;
        #pragma unroll
        for (int q = 0; q < BLOCK / 64; q++) s += s_red[q];
        partial[bid] = s;
    }
}

// Final reduction: one block sums the 576 per-block partials.
__global__ __launch_bounds__(BLOCK) void yolo_reduce(const float* __restrict__ partial,
                                                     float* __restrict__ d_out) {
    int t = threadIdx.x;
    __shared__ float s_red[BLOCK / 64];
    float s = 0.f;
    for (int i = t; i < GRID; i += BLOCK) s += partial[i];
    #pragma unroll
    for (int off = 32; off; off >>= 1) s += __shfl_down(s, off);
    if ((t & 63) == 0) s_red[t >> 6] = s;
    __syncthreads();
    if (t == 0) {
        float tot = 0.f;
        #pragma unroll
        for (int q = 0; q < BLOCK / 64; q++) tot += s_red[q];
        d_out[0] = tot;
    }
}

extern "C" void kernel_launch(void* const* d_in, const int* in_sizes, int n_in,
                              void* d_out, int out_size, void* d_ws, size_t ws_size,
                              hipStream_t stream) {
    const float* out = (const float*)d_in[0];
    const float* target = (const float*)d_in[1];
    float* partial = (float*)d_ws;
    float* o = (float*)d_out;

    hipLaunchKernelGGL(yolo_fused, dim3(GRID), dim3(BLOCK), 0, stream,
                       out, target, partial);
    hipLaunchKernelGGL(yolo_reduce, dim3(1), dim3(BLOCK), 0, stream,
                       partial, o);
}